// Round 4
// baseline (91.864 us; speedup 1.0000x reference)
//
#include <hip/hip_runtime.h>

#define NPTS 8192

typedef __attribute__((ext_vector_type(8))) short bf16x8;
typedef __attribute__((ext_vector_type(4))) float f32x4;
typedef unsigned short ushort_t;
typedef unsigned int uint_t;

// exp argument (base-2): arg = C1*(ni+nj) + K2*dot6(x_i,x_j)
#define C1f (-144.26950408889634f)   // -100*log2(e)
#define K2f (288.53900817779268f)    // +200*log2(e)
// out = s*exp(-20*pen) = s*exp2(C2*pen)
#define C2f (-28.853900817779268f)
#define SQK2f (16.98643596886418f)   // sqrt(K2f)

static __device__ __forceinline__ ushort_t f2b(float f) {
    union { float f; uint_t u; } v; v.f = f;
    uint_t u = v.u;
    uint_t r = (u + 0x7FFFu + ((u >> 16) & 1u)) >> 16;   // RN-even
    return (ushort_t)r;
}
static __device__ __forceinline__ float b2f(ushort_t h) {
    union { uint_t u; float f; } v; v.u = ((uint_t)h) << 16;
    return v.f;
}

// Build per-point 32-dim bf16 embedding columns so that
//   sum_k Acol_i[k]*Bcol_j[k] = C1*(ni+nj) + K2*dot6(x_i, x_j)   (= exp2 arg)
// k 0-5 : A=u_hi      B=u_hi      (u = sqrt(K2)*x, exact hi/lo split)
// k 6-11: A=u_hi      B=u_lo
// k12-17: A=u_lo      B=u_hi
// k18-23: A=u_lo      B=u_lo
// k24-26: A=c_hi/m/l  B=1         (c = C1*ni, 3-way bf16 split)
// k27-29: A=1         B=c_hi/m/l
// k30-31: 0
__global__ __launch_bounds__(256) void prep_kernel(
    const float* __restrict__ src, const float* __restrict__ tgt,
    const float* __restrict__ scores,
    ushort_t* __restrict__ Ag, ushort_t* __restrict__ Bg,
    float* __restrict__ penalty)
{
    const int i = blockIdx.x * 256 + threadIdx.x;
    if (i >= NPTS) return;

    float x[6];
    x[0] = src[i * 3 + 0]; x[1] = src[i * 3 + 1]; x[2] = src[i * 3 + 2];
    x[3] = tgt[i * 3 + 0]; x[4] = tgt[i * 3 + 1]; x[5] = tgt[i * 3 + 2];

    float n = 0.0f;
    #pragma unroll
    for (int d = 0; d < 6; d++) n += x[d] * x[d];
    float c = C1f * n;

    ushort_t uh[6], ul[6];
    #pragma unroll
    for (int d = 0; d < 6; d++) {
        float u  = SQK2f * x[d];
        ushort_t h = f2b(u);
        float    r = u - b2f(h);
        uh[d] = h;
        ul[d] = f2b(r);
    }
    ushort_t ch = f2b(c);
    float    r1 = c - b2f(ch);
    ushort_t cm = f2b(r1);
    ushort_t cl = f2b(r1 - b2f(cm));
    const ushort_t one = 0x3F80;

    ushort_t A[32], B[32];
    #pragma unroll
    for (int k = 0; k < 32; k++) { A[k] = 0; B[k] = 0; }
    #pragma unroll
    for (int d = 0; d < 6; d++) {
        A[d]      = uh[d];  B[d]      = uh[d];
        A[6 + d]  = uh[d];  B[6 + d]  = ul[d];
        A[12 + d] = ul[d];  B[12 + d] = uh[d];
        A[18 + d] = ul[d];  B[18 + d] = ul[d];
    }
    A[24] = ch;  A[25] = cm;  A[26] = cl;
    B[24] = one; B[25] = one; B[26] = one;
    A[27] = one; A[28] = one; A[29] = one;
    B[27] = ch;  B[28] = cm;  B[29] = cl;

    uint4* Ao = (uint4*)(Ag + (size_t)i * 32);
    uint4* Bo = (uint4*)(Bg + (size_t)i * 32);
    const uint4* As = (const uint4*)A;
    const uint4* Bs = (const uint4*)B;
    #pragma unroll
    for (int w = 0; w < 4; w++) { O: ; Ao[w] = As[w]; Bo[w] = Bs[w]; }

    penalty[i] = 0.0f;
}

// Each wave: 4 row-strips of 16 (64 rows) x 256 j's (16 MFMA tiles).
// A-frag: A[m][k], m = lane&15, k = (lane>>4)*8 + idx.
// B-frag: B[k][n], n = lane&15, k = (lane>>4)*8 + idx.
// C/D   : col = lane&15, row = (lane>>4)*4 + reg.
__global__ __launch_bounds__(256) void main_kernel(
    const ushort_t* __restrict__ Ag, const ushort_t* __restrict__ Bg,
    const float* __restrict__ scores, float* __restrict__ penalty)
{
    const int t    = threadIdx.x;
    const int lane = t & 63;
    const int wid  = t >> 6;
    const int half = lane & 15;
    const int quad = lane >> 4;
    const int iw   = blockIdx.x * 64;
    const int js   = blockIdx.y * 4 + wid;
    const int j0w  = js * 256;

    bf16x8 afrag[4];
    #pragma unroll
    for (int s = 0; s < 4; s++) {
        int row = iw + s * 16 + half;
        afrag[s] = *(const bf16x8*)(Ag + (size_t)row * 32 + quad * 8);
    }

    float si[4][4];
    float acc[4][4];
    #pragma unroll
    for (int s = 0; s < 4; s++)
        #pragma unroll
        for (int r = 0; r < 4; r++) {
            si[s][r]  = scores[iw + s * 16 + quad * 4 + r];
            acc[s][r] = 0.0f;
        }

    const f32x4 zero = {0.0f, 0.0f, 0.0f, 0.0f};

    for (int tt = 0; tt < 16; tt++) {
        const int j0 = j0w + tt * 16;
        bf16x8 bfrag = *(const bf16x8*)(Bg + (size_t)(j0 + half) * 32 + quad * 8);
        float  sj    = scores[j0 + half];
        #pragma unroll
        for (int s = 0; s < 4; s++) {
            f32x4 d = __builtin_amdgcn_mfma_f32_16x16x32_bf16(
                afrag[s], bfrag, zero, 0, 0, 0);
            #pragma unroll
            for (int r = 0; r < 4; r++) {
                float cl = __builtin_amdgcn_exp2f(d[r]);
                acc[s][r] += (sj > si[s][r]) ? cl : 0.0f;
            }
        }
    }

    // reduce across the 16 columns (lanes sharing the same quad)
    #pragma unroll
    for (int s = 0; s < 4; s++)
        #pragma unroll
        for (int r = 0; r < 4; r++) {
            float v = acc[s][r];
            v += __shfl_xor(v, 1);
            v += __shfl_xor(v, 2);
            v += __shfl_xor(v, 4);
            v += __shfl_xor(v, 8);
            if (half == 0)
                atomicAdd(&penalty[iw + s * 16 + quad * 4 + r], v);
        }
}

__global__ __launch_bounds__(256) void fin_kernel(
    const float* __restrict__ scores, const float* __restrict__ penalty,
    float* __restrict__ out)
{
    const int i = blockIdx.x * 256 + threadIdx.x;
    if (i < NPTS)
        out[i] = scores[i] * __builtin_amdgcn_exp2f(C2f * penalty[i]);
}

extern "C" void kernel_launch(void* const* d_in, const int* in_sizes, int n_in,
                              void* d_out, int out_size, void* d_ws, size_t ws_size,
                              hipStream_t stream) {
    const float* src    = (const float*)d_in[0];
    const float* tgt    = (const float*)d_in[1];
    const float* scores = (const float*)d_in[2];
    float* out = (float*)d_out;

    char* ws = (char*)d_ws;
    ushort_t* Ag      = (ushort_t*)(ws);                       // 512 KB
    ushort_t* Bg      = (ushort_t*)(ws + 524288);              // 512 KB
    float*    penalty = (float*)   (ws + 1048576);             // 32 KB

    prep_kernel<<<NPTS / 256, 256, 0, stream>>>(src, tgt, scores, Ag, Bg, penalty);
    main_kernel<<<dim3(128, 8), 256, 0, stream>>>(Ag, Bg, scores, penalty);
    fin_kernel<<<NPTS / 256, 256, 0, stream>>>(scores, penalty, out);
}

// Round 5
// 83.859 us; speedup vs baseline: 1.0955x; 1.0955x over previous
//
#include <hip/hip_runtime.h>

#define NPTS 8192

typedef __attribute__((ext_vector_type(8))) short bf16x8;
typedef __attribute__((ext_vector_type(4))) float f32x4;
typedef unsigned short u16;
typedef unsigned int u32;

// arg(base2) = C1*(ni+nj) + K2*dot6 ; closeness^2 = exp2(arg)
#define C1f (-144.26950408889634f)   // -100*log2(e)
#define K2f (288.53900817779268f)
#define C2f (-28.853900817779268f)   // out = s*exp2(C2*pen)
#define SQK2f (16.98643596886418f)   // sqrt(K2)
#define SKIP_TH (-50.0f)             // exp2(-50)*8192 ~ 1e-11 penalty err

static __device__ __forceinline__ u16 f2b(float f) {
    union { float f; u32 u; } v; v.f = f;
    u32 u = v.u;
    return (u16)((u + 0x7FFFu + ((u >> 16) & 1u)) >> 16);   // RN-even
}
static __device__ __forceinline__ float b2f(u16 h) {
    union { u32 u; float f; } v; v.u = ((u32)h) << 16;
    return v.f;
}

struct __align__(16) Emb {
    u16 a[32];     // A-operand column (64 B)
    u16 b[32];     // B-operand column (64 B)
    float sc;      // score
    u32 pad[3];    // -> 144 B row (16B-aligned stride)
};

// Same verified split as R4: dot(A_i, B_j) = C1*(ni+nj) + K2*dot6(x_i,x_j)
static __device__ __forceinline__ void embed(
    const float* __restrict__ src, const float* __restrict__ tgt,
    const float* __restrict__ scores, int p, Emb* dst)
{
    float x[6];
    x[0] = src[p * 3 + 0]; x[1] = src[p * 3 + 1]; x[2] = src[p * 3 + 2];
    x[3] = tgt[p * 3 + 0]; x[4] = tgt[p * 3 + 1]; x[5] = tgt[p * 3 + 2];

    float n = 0.0f;
    #pragma unroll
    for (int d = 0; d < 6; d++) n += x[d] * x[d];
    float c = C1f * n;

    u16 uh[6], ul[6];
    #pragma unroll
    for (int d = 0; d < 6; d++) {
        float u  = SQK2f * x[d];
        u16   h  = f2b(u);
        uh[d] = h;
        ul[d] = f2b(u - b2f(h));
    }
    u16   ch = f2b(c);
    float r1 = c - b2f(ch);
    u16   cm = f2b(r1);
    u16   cl = f2b(r1 - b2f(cm));
    const u32 one = 0x3F80u;

    #define PK(lo, hi) (((u32)(u16)(lo)) | (((u32)(u16)(hi)) << 16))
    uint4 a0 = make_uint4(PK(uh[0],uh[1]), PK(uh[2],uh[3]), PK(uh[4],uh[5]), PK(uh[0],uh[1]));
    uint4 a1 = make_uint4(PK(uh[2],uh[3]), PK(uh[4],uh[5]), PK(ul[0],ul[1]), PK(ul[2],ul[3]));
    uint4 a2 = make_uint4(PK(ul[4],ul[5]), PK(ul[0],ul[1]), PK(ul[2],ul[3]), PK(ul[4],ul[5]));
    uint4 a3 = make_uint4(PK(ch, cm),      PK(cl, one),     PK(one, one),    0u);
    uint4 b0 = make_uint4(PK(uh[0],uh[1]), PK(uh[2],uh[3]), PK(uh[4],uh[5]), PK(ul[0],ul[1]));
    uint4 b1 = make_uint4(PK(ul[2],ul[3]), PK(ul[4],ul[5]), PK(uh[0],uh[1]), PK(uh[2],uh[3]));
    uint4 b2 = make_uint4(PK(uh[4],uh[5]), PK(ul[0],ul[1]), PK(ul[2],ul[3]), PK(ul[4],ul[5]));
    uint4 b3 = make_uint4(PK(one, one),    PK(one, ch),     PK(cm, cl),      0u);
    #undef PK

    uint4* da = (uint4*)dst->a;
    uint4* db = (uint4*)dst->b;
    da[0] = a0; da[1] = a1; da[2] = a2; da[3] = a3;
    db[0] = b0; db[1] = b1; db[2] = b2; db[3] = b3;
    dst->sc = scores[p];
}

// Grid (128, 8): bx -> 64 i-rows, by -> 1024 j's. 4 waves split j into 4x256.
// A-frag: A[m][k], m=lane&15, k=(lane>>4)*8+idx. C/D: col=lane&15, row=(lane>>4)*4+r.
__global__ __launch_bounds__(256, 4) void softnms_kernel(
    const float* __restrict__ src, const float* __restrict__ tgt,
    const float* __restrict__ scores,
    float* __restrict__ penalty, u32* __restrict__ cnt,
    float* __restrict__ out)
{
    __shared__ Emb emb[256];        // 36 KB
    __shared__ u32 lastflag;

    const int t    = threadIdx.x;
    const int lane = t & 63;
    const int wid  = t >> 6;
    const int half = lane & 15;
    const int quad = lane >> 4;
    const int iw   = blockIdx.x * 64;

    // ---- phase A: embed own 64 i-rows into LDS, pull frags/scores ----
    if (t < 64) embed(src, tgt, scores, iw + t, &emb[t]);
    __syncthreads();

    bf16x8 afrag[4];
    float si[4][4], acc[4][4];
    #pragma unroll
    for (int s = 0; s < 4; s++) {
        afrag[s] = *(const bf16x8*)(emb[s * 16 + half].a + quad * 8);
        #pragma unroll
        for (int r = 0; r < 4; r++) {
            si[s][r]  = emb[s * 16 + quad * 4 + r].sc;
            acc[s][r] = 0.0f;
        }
    }
    __syncthreads();

    const f32x4 zero = {0.0f, 0.0f, 0.0f, 0.0f};

    // ---- phase B: 4 chunks of 256 j ----
    for (int c = 0; c < 4; c++) {
        const int j0 = blockIdx.y * 1024 + c * 256;
        embed(src, tgt, scores, j0 + t, &emb[t]);
        __syncthreads();

        #pragma unroll
        for (int u = 0; u < 4; u++) {
            const int tt = wid * 4 + u;
            bf16x8 bfrag = *(const bf16x8*)(emb[tt * 16 + half].b + quad * 8);
            float  sj    = emb[tt * 16 + half].sc;

            f32x4 d[4];
            #pragma unroll
            for (int s = 0; s < 4; s++)
                d[s] = __builtin_amdgcn_mfma_f32_16x16x32_bf16(
                    afrag[s], bfrag, zero, 0, 0, 0);

            float m = d[0][0];
            #pragma unroll
            for (int s = 0; s < 4; s++)
                #pragma unroll
                for (int r = 0; r < 4; r++) m = fmaxf(m, d[s][r]);

            if (__any(m > SKIP_TH)) {
                #pragma unroll
                for (int s = 0; s < 4; s++)
                    #pragma unroll
                    for (int r = 0; r < 4; r++) {
                        float cl = __builtin_amdgcn_exp2f(d[s][r]);
                        acc[s][r] += (sj > si[s][r]) ? cl : 0.0f;
                    }
            }
        }
        __syncthreads();
    }

    // ---- reduce over 16 columns (half bits), accumulate to global ----
    #pragma unroll
    for (int s = 0; s < 4; s++)
        #pragma unroll
        for (int r = 0; r < 4; r++) {
            float v = acc[s][r];
            v += __shfl_xor(v, 1);
            v += __shfl_xor(v, 2);
            v += __shfl_xor(v, 4);
            v += __shfl_xor(v, 8);
            if (half == 0)
                atomicAdd(&penalty[iw + s * 16 + quad * 4 + r], v);
        }

    // ---- last block of this i-group finalizes ----
    __syncthreads();                 // drains the atomics (vmcnt before barrier)
    if (t == 0) {
        __threadfence();             // release our penalty adds
        u32 old = atomicAdd(&cnt[blockIdx.x], 1u);
        lastflag = (old == 7u) ? 1u : 0u;
    }
    __syncthreads();
    if (lastflag && t < 64) {
        __threadfence();             // acquire others' penalty adds
        float p = __hip_atomic_load(&penalty[iw + t], __ATOMIC_RELAXED,
                                    __HIP_MEMORY_SCOPE_AGENT);
        out[iw + t] = scores[iw + t] * __builtin_amdgcn_exp2f(C2f * p);
    }
}

extern "C" void kernel_launch(void* const* d_in, const int* in_sizes, int n_in,
                              void* d_out, int out_size, void* d_ws, size_t ws_size,
                              hipStream_t stream) {
    const float* src    = (const float*)d_in[0];
    const float* tgt    = (const float*)d_in[1];
    const float* scores = (const float*)d_in[2];
    float* out = (float*)d_out;

    float* penalty = (float*)d_ws;                         // 32 KB
    u32*   cnt     = (u32*)((char*)d_ws + 32768);          // 512 B

    hipMemsetAsync(d_ws, 0, 33280, stream);
    softnms_kernel<<<dim3(128, 8), 256, 0, stream>>>(
        src, tgt, scores, penalty, cnt, out);
}

// Round 6
// 80.018 us; speedup vs baseline: 1.1480x; 1.0480x over previous
//
#include <hip/hip_runtime.h>

#define NPTS 8192
#define BLOCK 512
#define IB 32                    // i-rows per block
#define NBLK (NPTS / IB)         // 256 blocks = 1 per CU
#define CH 512                   // j-chunk staged in LDS
#define NCH (NPTS / CH)          // 16 chunks

typedef __attribute__((ext_vector_type(8))) short bf16x8;
typedef __attribute__((ext_vector_type(4))) float f32x4;
typedef unsigned short u16;
typedef unsigned int u32;

// arg(base2) = C1*(ni+nj) + K2*dot6 ; closeness^2 = exp2(arg)
#define C1f (-144.26950408889634f)   // -100*log2(e)
#define K2f (288.53900817779268f)
#define C2f (-28.853900817779268f)   // out = s*exp2(C2*pen)
#define SQK2f (16.98643596886418f)   // sqrt(K2)
#define SKIP_TH (-50.0f)             // exp2(-50)*8192 ~ 1e-11 penalty err

static __device__ __forceinline__ u16 f2b(float f) {
    union { float f; u32 u; } v; v.f = f;
    u32 u = v.u;
    return (u16)((u + 0x7FFFu + ((u >> 16) & 1u)) >> 16);   // RN-even
}
static __device__ __forceinline__ float b2f(u16 h) {
    union { u32 u; float f; } v; v.u = ((u32)h) << 16;
    return v.f;
}

struct Split {
    u16 uh[6], ul[6], ch, cm, cl;
    float sc;
};

static __device__ __forceinline__ Split mksplit(
    const float* __restrict__ src, const float* __restrict__ tgt,
    const float* __restrict__ scores, int p)
{
    float x[6];
    x[0] = src[p * 3 + 0]; x[1] = src[p * 3 + 1]; x[2] = src[p * 3 + 2];
    x[3] = tgt[p * 3 + 0]; x[4] = tgt[p * 3 + 1]; x[5] = tgt[p * 3 + 2];

    float n = 0.0f;
    #pragma unroll
    for (int d = 0; d < 6; d++) n += x[d] * x[d];
    float c = C1f * n;

    Split s;
    #pragma unroll
    for (int d = 0; d < 6; d++) {
        float u = SQK2f * x[d];
        u16   h = f2b(u);
        s.uh[d] = h;
        s.ul[d] = f2b(u - b2f(h));
    }
    s.ch = f2b(c);
    float r1 = c - b2f(s.ch);
    s.cm = f2b(r1);
    s.cl = f2b(r1 - b2f(s.cm));
    s.sc = scores[p];
    return s;
}

#define PK(lo, hi) (((u32)(u16)(lo)) | (((u32)(u16)(hi)) << 16))
static __device__ __forceinline__ void emit_a(const Split& s, uint4* da) {
    const u32 one = 0x3F80u;
    da[0] = make_uint4(PK(s.uh[0],s.uh[1]), PK(s.uh[2],s.uh[3]), PK(s.uh[4],s.uh[5]), PK(s.uh[0],s.uh[1]));
    da[1] = make_uint4(PK(s.uh[2],s.uh[3]), PK(s.uh[4],s.uh[5]), PK(s.ul[0],s.ul[1]), PK(s.ul[2],s.ul[3]));
    da[2] = make_uint4(PK(s.ul[4],s.ul[5]), PK(s.ul[0],s.ul[1]), PK(s.ul[2],s.ul[3]), PK(s.ul[4],s.ul[5]));
    da[3] = make_uint4(PK(s.ch, s.cm),      PK(s.cl, one),       PK(one, one),        0u);
}
static __device__ __forceinline__ void emit_b(const Split& s, uint4* db) {
    const u32 one = 0x3F80u;
    db[0] = make_uint4(PK(s.uh[0],s.uh[1]), PK(s.uh[2],s.uh[3]), PK(s.uh[4],s.uh[5]), PK(s.ul[0],s.ul[1]));
    db[1] = make_uint4(PK(s.ul[2],s.ul[3]), PK(s.ul[4],s.ul[5]), PK(s.uh[0],s.uh[1]), PK(s.uh[2],s.uh[3]));
    db[2] = make_uint4(PK(s.uh[4],s.uh[5]), PK(s.ul[0],s.ul[1]), PK(s.ul[2],s.ul[3]), PK(s.ul[4],s.ul[5]));
    db[3] = make_uint4(PK(one, one),        PK(one, s.ch),       PK(s.cm, s.cl),      0u);
}
#undef PK

// One block = 32 i-rows x ALL j. A-frag: A[m][k], m=lane&15, k=(lane>>4)*8+idx.
// C/D: col=lane&15, row=(lane>>4)*4+r.  8 waves each own 4 j-tiles per chunk.
__global__ __launch_bounds__(BLOCK, 2) void softnms_kernel(
    const float* __restrict__ src, const float* __restrict__ tgt,
    const float* __restrict__ scores, float* __restrict__ out)
{
    __shared__ uint4 bcol[2][CH * 4];    // 64 KB (double-buffered B columns)
    __shared__ float scj[2][CH];         //  4 KB
    __shared__ uint4 acol[IB * 4];       //  2 KB
    __shared__ float sti[IB];
    __shared__ float red[8][IB];         //  1 KB

    const int t    = threadIdx.x;
    const int lane = t & 63;
    const int wid  = t >> 6;
    const int half = lane & 15;
    const int quad = lane >> 4;
    const int i0   = blockIdx.x * IB;

    // prologue: embed own 32 i's + chunk-0 j's
    if (t < IB) {
        Split s = mksplit(src, tgt, scores, i0 + t);
        emit_a(s, &acol[t * 4]);
        sti[t] = s.sc;
    }
    {
        Split s = mksplit(src, tgt, scores, t);
        emit_b(s, &bcol[0][t * 4]);
        scj[0][t] = s.sc;
    }
    __syncthreads();

    bf16x8 afrag[2];
    float si[2][4], acc[2][4];
    #pragma unroll
    for (int s = 0; s < 2; s++) {
        afrag[s] = *(const bf16x8*)((const u16*)acol + (s * 16 + half) * 32 + quad * 8);
        #pragma unroll
        for (int r = 0; r < 4; r++) {
            si[s][r]  = sti[s * 16 + quad * 4 + r];
            acc[s][r] = 0.0f;
        }
    }

    const f32x4 zero = {0.0f, 0.0f, 0.0f, 0.0f};

    for (int c = 0; c < NCH; c++) {
        const int cur = c & 1;
        const int nxt = cur ^ 1;

        // embed next chunk into the other buffer (global loads issue early;
        // writes race only with chunk c-1 readers, all past the last barrier)
        if (c + 1 < NCH) {
            Split s = mksplit(src, tgt, scores, (c + 1) * CH + t);
            emit_b(s, &bcol[nxt][t * 4]);
            scj[nxt][t] = s.sc;
        }

        // compute current chunk: 32 j-tiles, 4 per wave
        #pragma unroll
        for (int u = 0; u < 4; u++) {
            const int tt = wid * 4 + u;
            bf16x8 bfrag = *(const bf16x8*)((const u16*)&bcol[cur][0]
                                            + (tt * 16 + half) * 32 + quad * 8);
            float sj = scj[cur][tt * 16 + half];

            f32x4 d0 = __builtin_amdgcn_mfma_f32_16x16x32_bf16(afrag[0], bfrag, zero, 0, 0, 0);
            f32x4 d1 = __builtin_amdgcn_mfma_f32_16x16x32_bf16(afrag[1], bfrag, zero, 0, 0, 0);

            float m0 = fmaxf(fmaxf(d0[0], d0[1]), fmaxf(d0[2], d0[3]));
            float m1 = fmaxf(fmaxf(d1[0], d1[1]), fmaxf(d1[2], d1[3]));
            if (__any(fmaxf(m0, m1) > SKIP_TH)) {
                #pragma unroll
                for (int r = 0; r < 4; r++) {
                    float c0 = __builtin_amdgcn_exp2f(d0[r]);
                    float c1 = __builtin_amdgcn_exp2f(d1[r]);
                    acc[0][r] += (sj > si[0][r]) ? c0 : 0.0f;
                    acc[1][r] += (sj > si[1][r]) ? c1 : 0.0f;
                }
            }
        }
        __syncthreads();
    }

    // reduce over the 16 columns (half bits), then across 8 waves
    #pragma unroll
    for (int s = 0; s < 2; s++)
        #pragma unroll
        for (int r = 0; r < 4; r++) {
            float v = acc[s][r];
            v += __shfl_xor(v, 1);
            v += __shfl_xor(v, 2);
            v += __shfl_xor(v, 4);
            v += __shfl_xor(v, 8);
            if (half == 0) red[wid][s * 16 + quad * 4 + r] = v;
        }
    __syncthreads();
    if (t < IB) {
        float p = 0.0f;
        #pragma unroll
        for (int w = 0; w < 8; w++) p += red[w][t];
        out[i0 + t] = sti[t] * __builtin_amdgcn_exp2f(C2f * p);
    }
}

extern "C" void kernel_launch(void* const* d_in, const int* in_sizes, int n_in,
                              void* d_out, int out_size, void* d_ws, size_t ws_size,
                              hipStream_t stream) {
    const float* src    = (const float*)d_in[0];
    const float* tgt    = (const float*)d_in[1];
    const float* scores = (const float*)d_in[2];
    float* out = (float*)d_out;

    softnms_kernel<<<NBLK, BLOCK, 0, stream>>>(src, tgt, scores, out);
}